// Round 3
// baseline (424.304 us; speedup 1.0000x reference)
//
#include <hip/hip_runtime.h>

#define NT 65536
#define MD 1024
#define NE 64
#define BK 32
#define NBLK (NT / 64)   // 1024 gate blocks, 64 tokens each

// swizzled column chunk: kills bank conflicts without padding (keeps b128 align)
#define SWZ(r, q) (((q) ^ (((r) >> 2) & 7)))

// ---------------------------------------------------------------------------
// Kernel 1: fused gating GEMM + argmax + softmax + rank/hist + me accumulation.
// 64 tokens x 64 experts per block, 256 threads, 4x4 per-thread tile.
// Row-major swizzled LDS tiles: b128 writes AND b128 reads, no transpose.
// ---------------------------------------------------------------------------
__global__ __launch_bounds__(256, 4) void gate_kernel(
    const float* __restrict__ x, const float* __restrict__ wg,
    float* __restrict__ out, unsigned* __restrict__ packed_ws,
    int* __restrict__ hist_ws, float* __restrict__ me)
{
    // rows 0..63 = x tokens, rows 64..127 = experts; 32 floats (one BK slice)
    __shared__ __align__(16) float smem[2][128][32];   // 32 KB

    const int tid = threadIdx.x;
    const int tx = tid & 15;   // expert quad 0..15
    const int ty = tid >> 4;   // token quad 0..15
    const int t0 = blockIdx.x * 64;

    // staging: thread owns rows sr, sr+32 of x and of wg, chunk sq
    const int sr = tid >> 3;   // 0..31
    const int sq = tid & 7;    // 0..7
    const float* px0 = x  + (size_t)(t0 + sr) * MD + sq * 4;
    const float* px1 = px0 + (size_t)32 * MD;
    const float* pw0 = wg + (size_t)sr * MD + sq * 4;
    const float* pw1 = pw0 + (size_t)32 * MD;

    float4 g0 = *(const float4*)px0;
    float4 g1 = *(const float4*)px1;
    float4 g2 = *(const float4*)pw0;
    float4 g3 = *(const float4*)pw1;

#define STG(buf)                                                         \
    do {                                                                 \
        *(float4*)&smem[buf][sr      ][SWZ(sr,      sq) * 4] = g0;       \
        *(float4*)&smem[buf][sr + 32 ][SWZ(sr + 32, sq) * 4] = g1;       \
        *(float4*)&smem[buf][sr + 64 ][SWZ(sr + 64, sq) * 4] = g2;       \
        *(float4*)&smem[buf][sr + 96 ][SWZ(sr + 96, sq) * 4] = g3;       \
    } while (0)

    STG(0);
    __syncthreads();

    float acc[4][4];
#pragma unroll
    for (int i = 0; i < 4; ++i)
#pragma unroll
        for (int j = 0; j < 4; ++j) acc[i][j] = 0.f;

    for (int it = 0; it < MD / BK; ++it) {
        const int cur = it & 1;
        if (it < MD / BK - 1) {
            const int kn = (it + 1) * BK;
            g0 = *(const float4*)(px0 + kn);
            g1 = *(const float4*)(px1 + kn);
            g2 = *(const float4*)(pw0 + kn);
            g3 = *(const float4*)(pw1 + kn);
        }
#pragma unroll
        for (int q = 0; q < 8; ++q) {
            float4 A[4], B[4];
#pragma unroll
            for (int i = 0; i < 4; ++i)
                A[i] = *(const float4*)&smem[cur][ty * 4 + i][SWZ(ty * 4 + i, q) * 4];
#pragma unroll
            for (int j = 0; j < 4; ++j)
                B[j] = *(const float4*)&smem[cur][64 + tx * 4 + j][SWZ(64 + tx * 4 + j, q) * 4];
#pragma unroll
            for (int i = 0; i < 4; ++i)
#pragma unroll
                for (int j = 0; j < 4; ++j) {
                    acc[i][j] = fmaf(A[i].x, B[j].x, acc[i][j]);
                    acc[i][j] = fmaf(A[i].y, B[j].y, acc[i][j]);
                    acc[i][j] = fmaf(A[i].z, B[j].z, acc[i][j]);
                    acc[i][j] = fmaf(A[i].w, B[j].w, acc[i][j]);
                }
        }
        if (it < MD / BK - 1) STG(cur ^ 1);
        __syncthreads();
    }

    // ---- epilogue ----
    float* lt  = &smem[0][0][0];         // 64 x 65 logits tile
    float* inv = lt + 4160;              // 64 softmax reciprocals

#pragma unroll
    for (int i = 0; i < 4; ++i)
#pragma unroll
        for (int j = 0; j < 4; ++j)
            lt[(ty * 4 + i) * 65 + tx * 4 + j] = acc[i][j];
    __syncthreads();

    if (tid < 64) {
        const int t = tid;
        float m = -1e30f; int am = 0;
        for (int e = 0; e < NE; ++e) {
            float v = lt[t * 65 + e];
            if (v > m) { m = v; am = e; }   // strict > : first-max like jnp.argmax
        }
        float s = 0.f;
        for (int e = 0; e < NE; ++e) {
            float ev = __expf(lt[t * 65 + e] - m);
            lt[t * 65 + e] = ev;
            s += ev;
        }
        float g = 1.0f / s;
        const int gt = t0 + t;
        out[1 + gt] = (float)am;            // indices1_s
        out[2 + 2 * NT + gt] = g;           // gates1_s
        inv[t] = g;

        // rank within block (token order == lane order) + per-expert count
        const unsigned long long below = (1ull << t) - 1ull;
        int rank = 0, mycnt = 0;
        for (int e = 0; e < NE; ++e) {
            unsigned long long msk = __ballot(am == e);
            if (t == e)  mycnt = (int)__popcll(msk);
            if (am == e) rank  = (int)__popcll(msk & below);
        }
        packed_ws[gt] = (unsigned)am | ((unsigned)rank << 8);
        hist_ws[blockIdx.x * NE + t] = mycnt;   // lane t reports expert t's count
    }
    __syncthreads();

    if (tid < NE) {
        const int e = tid;
        float s = 0.f;
        for (int t = 0; t < 64; ++t) s += lt[t * 65 + e] * inv[t];
        atomicAdd(&me[e], s);
    }
}

// ---------------------------------------------------------------------------
// Kernel 2: per-expert exclusive scan over the 1024 block histograms
// (in-place: hist_ws becomes block offsets). Also emits ce[e] = total.
// ---------------------------------------------------------------------------
__global__ __launch_bounds__(256) void scan_kernel(
    int* __restrict__ hist_ws, float* __restrict__ ce)
{
    const int e = blockIdx.x;
    const int tid = threadIdx.x;
    const int lane = tid & 63, wave = tid >> 6;
    __shared__ int wtot[4];

    int h[4];
#pragma unroll
    for (int j = 0; j < 4; ++j) h[j] = hist_ws[(tid * 4 + j) * NE + e];
    int s = h[0] + h[1] + h[2] + h[3];

    int scan = s;
#pragma unroll
    for (int d = 1; d < 64; d <<= 1) {
        int o = __shfl_up(scan, d, 64);
        if (lane >= d) scan += o;
    }
    if (lane == 63) wtot[wave] = scan;
    __syncthreads();
    int wpre = 0;
#pragma unroll
    for (int w = 0; w < 4; ++w)
        if (w < wave) wpre += wtot[w];

    int run = wpre + scan - s;   // exclusive prefix for this thread's 4 blocks
#pragma unroll
    for (int j = 0; j < 4; ++j) {
        hist_ws[(tid * 4 + j) * NE + e] = run;
        run += h[j];
    }
    if (tid == 255) ce[e] = (float)run;  // total tokens routed to expert e
}

// ---------------------------------------------------------------------------
// Kernel 3: locations1_s[i] = offs[block][expert] + rank_within_block.
// ---------------------------------------------------------------------------
__global__ __launch_bounds__(256) void emit_kernel(
    const unsigned* __restrict__ packed_ws, const int* __restrict__ offs_ws,
    float* __restrict__ out)
{
    const int i = blockIdx.x * 256 + threadIdx.x;
    const unsigned p = packed_ws[i];
    const int am = (int)(p & 63u);
    const int rank = (int)(p >> 8);
    const int b = i >> 6;
    out[2 + NT + i] = (float)(offs_ws[b * NE + am] + rank);
}

// ---------------------------------------------------------------------------
// Kernel 4: l_aux + scalar outputs.
// ---------------------------------------------------------------------------
__global__ void finalize_kernel(const float* __restrict__ me,
                                const float* __restrict__ ce,
                                float* __restrict__ out)
{
    int tid = threadIdx.x;  // 64 threads = 1 wave
    float v = me[tid] * ce[tid];
#pragma unroll
    for (int d = 32; d > 0; d >>= 1) v += __shfl_down(v, d, 64);
    if (tid == 0) {
        out[0] = v * (float)((double)NE / ((double)NT * (double)NT));
        out[1 + NT] = 1024.0f;      // capacity = ceil(N/E) * 1.0
        out[2 + 3 * NT] = 64.0f;    // E
    }
}

extern "C" void kernel_launch(void* const* d_in, const int* in_sizes, int n_in,
                              void* d_out, int out_size, void* d_ws, size_t ws_size,
                              hipStream_t stream)
{
    const float* x  = (const float*)d_in[0];
    const float* wg = (const float*)d_in[1];
    float* out = (float*)d_out;

    unsigned* packed_ws = (unsigned*)d_ws;                         // NT uints
    int* hist_ws = (int*)((char*)d_ws + (size_t)NT * 4);           // NBLK*NE ints
    float* me = (float*)((char*)d_ws + (size_t)NT * 4 + (size_t)NBLK * NE * 4);
    float* ce = me + NE;

    hipMemsetAsync(me, 0, NE * sizeof(float), stream);
    gate_kernel<<<NBLK, 256, 0, stream>>>(x, wg, out, packed_ws, hist_ws, me);
    scan_kernel<<<NE, 256, 0, stream>>>(hist_ws, ce);
    emit_kernel<<<NT / 256, 256, 0, stream>>>(packed_ws, hist_ws, out);
    finalize_kernel<<<1, 64, 0, stream>>>(me, ce, out);
}